// Round 1
// baseline (913.886 us; speedup 1.0000x reference)
//
#include <hip/hip_runtime.h>

typedef unsigned short u16;
typedef unsigned int u32;
typedef __bf16 bf16x8 __attribute__((ext_vector_type(8)));
typedef float f32x4 __attribute__((ext_vector_type(4)));

#define MFMA16(a, b, c) __builtin_amdgcn_mfma_f32_16x16x32_bf16((a), (b), (c), 0, 0, 0)

// ---- constants ----
#define S_LEN 2048
#define D_HEAD 128
#define NHEADS 16
#define NBH 32          // B*HEADS
#define QDIM 2048
#define NPROJ 22528     // 3*INNER + 2*MLP_HID
#define NCAT 10240      // INNER + MLP_HID
#define MROWS 4096      // B*S

__device__ __forceinline__ float bf2f(u16 u) { return __uint_as_float(((u32)u) << 16); }
__device__ __forceinline__ u16 f2bf(float f) {
  u32 u = __float_as_uint(f);
  return (u16)((u + 0x7FFFu + ((u >> 16) & 1u)) >> 16);
}
__device__ __forceinline__ void gld16(const void* g, void* l) {
  __builtin_amdgcn_global_load_lds((__attribute__((address_space(1))) void*)(g),
                                   (__attribute__((address_space(3))) void*)(l), 16, 0, 0);
}

// ---------------- f32 -> bf16 elementwise (vectorized) ----------------
__global__ __launch_bounds__(256) void f32_to_bf16(const float* __restrict__ in,
                                                   u16* __restrict__ out) {
  const u32 i = blockIdx.x * 256 + threadIdx.x;  // one float4 per thread
  const float4 v = ((const float4*)in)[i];
  uint2 o;
  o.x = (u32)f2bf(v.x) | ((u32)f2bf(v.y) << 16);
  o.y = (u32)f2bf(v.z) | ((u32)f2bf(v.w) << 16);
  ((uint2*)out)[i] = o;
}

// ---------------- tiled transpose-convert: in[R][C] f32 -> out[C][R] bf16 ----------------
__global__ __launch_bounds__(256) void transpose_f32_bf16(const float* __restrict__ in,
                                                          u16* __restrict__ out, int R, int C) {
  __shared__ u16 tile[64][65];
  const int tx = threadIdx.x & 63;
  const int ty = threadIdx.x >> 6;
  const int c0 = blockIdx.x * 64;
  const int r0 = blockIdx.y * 64;
#pragma unroll
  for (int it = 0; it < 16; ++it) {
    const int rr = ty * 16 + it;
    tile[rr][tx] = f2bf(in[(size_t)(r0 + rr) * C + c0 + tx]);
  }
  __syncthreads();
#pragma unroll
  for (int it = 0; it < 16; ++it) {
    const int rr = ty * 16 + it;
    out[(size_t)(c0 + rr) * R + r0 + tx] = tile[tx][rr];
  }
}

// ---------------- batched bf16 transpose: in[z][R][C] -> out[z][C][R] ----------------
__global__ __launch_bounds__(256) void transpose_bf16_b(const u16* __restrict__ in,
                                                        u16* __restrict__ out, int R, int C) {
  __shared__ u16 tile[64][65];
  const int z = blockIdx.z;
  in += (size_t)z * R * C;
  out += (size_t)z * R * C;
  const int tx = threadIdx.x & 63;
  const int ty = threadIdx.x >> 6;
  const int c0 = blockIdx.x * 64;
  const int r0 = blockIdx.y * 64;
#pragma unroll
  for (int it = 0; it < 16; ++it) {
    const int rr = ty * 16 + it;
    tile[rr][tx] = in[(size_t)(r0 + rr) * C + c0 + tx];
  }
  __syncthreads();
#pragma unroll
  for (int it = 0; it < 16; ++it) {
    const int rr = ty * 16 + it;
    out[(size_t)(c0 + rr) * R + r0 + tx] = tile[tx][rr];
  }
}

// ---------------- bf16 GEMM: C[M][N] = A[M][K] * Bt[N][K]^T ----------------
// 128x128 tile, BK=64, 4 waves (2x2), each wave 64x64 = 4x4 frags of 16x16x32.
// LDS tiles [128 rows][64 k] bf16, XOR-swizzled (granule ^= row&7) on both the
// global_load_lds SOURCE address and the ds_read — linear LDS dest (rule #21).
template <int OUTF32>
__global__ __launch_bounds__(256, 2) void gemm_bt(const u16* __restrict__ A,
                                                  const u16* __restrict__ Bt,
                                                  void* __restrict__ Cvoid,
                                                  const float* __restrict__ bias, int N, int K) {
  __shared__ u16 As[128 * 64];
  __shared__ u16 Bs[128 * 64];
  const int t = threadIdx.x;
  const int l = t & 63;
  const int w = t >> 6;
  const int lr = l & 15;
  const int lg = l >> 4;
  const int m0 = blockIdx.y * 128;
  const int n0 = blockIdx.x * 128;
  const int wm = (w >> 1) * 64;
  const int wn = (w & 1) * 64;

  f32x4 acc[4][4] = {};
  const int obase = w * 1024 + l * 16;  // byte offset within 16KB tile

  for (int k0 = 0; k0 < K; k0 += 64) {
#pragma unroll
    for (int rnd = 0; rnd < 4; ++rnd) {
      const int o = obase + rnd * 4096;
      const int row = o >> 7;          // 128 B per row
      const int g = (o & 127) >> 4;    // 16B granule within row
      const int gs = g ^ (row & 7);    // pre-swizzle the SOURCE
      gld16(A + (size_t)(m0 + row) * K + k0 + gs * 8, &As[rnd * 2048 + w * 512]);
      gld16(Bt + (size_t)(n0 + row) * K + k0 + gs * 8, &Bs[rnd * 2048 + w * 512]);
    }
    __syncthreads();

    bf16x8 af[4][2], bfr[4][2];
#pragma unroll
    for (int i = 0; i < 4; ++i) {
#pragma unroll
      for (int kc = 0; kc < 2; ++kc) {
        const int ra = wm + i * 16 + lr;
        af[i][kc] = *(const bf16x8*)&As[ra * 64 + (((kc * 4 + lg) ^ (ra & 7)) * 8)];
        const int rb = wn + i * 16 + lr;
        bfr[i][kc] = *(const bf16x8*)&Bs[rb * 64 + (((kc * 4 + lg) ^ (rb & 7)) * 8)];
      }
    }
#pragma unroll
    for (int kc = 0; kc < 2; ++kc)
#pragma unroll
      for (int i = 0; i < 4; ++i)
#pragma unroll
        for (int j = 0; j < 4; ++j)
          acc[i][j] = MFMA16(af[i][kc], bfr[j][kc], acc[i][j]);
    __syncthreads();
  }

  if (OUTF32) {
    float* C = (float*)Cvoid;
#pragma unroll
    for (int i = 0; i < 4; ++i)
#pragma unroll
      for (int j = 0; j < 4; ++j)
#pragma unroll
        for (int r = 0; r < 4; ++r) {
          const int row = m0 + wm + i * 16 + lg * 4 + r;
          const int col = n0 + wn + j * 16 + lr;
          C[(size_t)row * N + col] = acc[i][j][r] + bias[col];
        }
  } else {
    u16* C = (u16*)Cvoid;
#pragma unroll
    for (int i = 0; i < 4; ++i)
#pragma unroll
      for (int j = 0; j < 4; ++j)
#pragma unroll
        for (int r = 0; r < 4; ++r) {
          const int row = m0 + wm + i * 16 + lg * 4 + r;
          const int col = n0 + wn + j * 16 + lr;
          C[(size_t)row * N + col] = f2bf(acc[i][j][r]);
        }
  }
}

// ---------------- fused RMSNorm + RoPE + split to Q/K/V [bh][s][d] ----------------
// one wave per (row, head); lane holds the interleaved pair (2l, 2l+1).
__global__ __launch_bounds__(256) void norm_rope(const u16* __restrict__ proj,
                                                 const float* __restrict__ cosT,
                                                 const float* __restrict__ sinT,
                                                 const float* __restrict__ wq,
                                                 const float* __restrict__ wk,
                                                 u16* __restrict__ Qb, u16* __restrict__ Kb,
                                                 u16* __restrict__ Vb) {
  const int l = threadIdx.x & 63;
  const int wg = blockIdx.x * 4 + (threadIdx.x >> 6);
  const int h = wg & 15;
  const int r = wg >> 4;       // 0..4095
  const int b = r >> 11;       // /S
  const int s = r & 2047;
  const int bh = (b << 4) + h;

  const u16* p = proj + (size_t)r * NPROJ + h * 128 + 2 * l;
  const u32 qu = *(const u32*)(p);
  const u32 ku = *(const u32*)(p + QDIM);
  const u32 vu = *(const u32*)(p + 2 * QDIM);

  const float q0 = bf2f(qu & 0xffff), q1 = bf2f(qu >> 16);
  const float k0 = bf2f(ku & 0xffff), k1 = bf2f(ku >> 16);

  float sq = q0 * q0 + q1 * q1;
  float sk = k0 * k0 + k1 * k1;
#pragma unroll
  for (int m = 1; m < 64; m <<= 1) {
    sq += __shfl_xor(sq, m);
    sk += __shfl_xor(sk, m);
  }
  const float scq = rsqrtf(sq * (1.0f / 128.0f) + 1e-5f);
  const float sck = rsqrtf(sk * (1.0f / 128.0f) + 1e-5f);

  const float2 cc = *(const float2*)&cosT[s * 128 + 2 * l];
  const float2 ssn = *(const float2*)&sinT[s * 128 + 2 * l];
  const float w0 = wq[2 * l], w1 = wq[2 * l + 1];
  const float x0 = wk[2 * l], x1 = wk[2 * l + 1];

  const float qn0 = q0 * scq * w0, qn1 = q1 * scq * w1;
  const float kn0 = k0 * sck * x0, kn1 = k1 * sck * x1;

  const float ATT = 0.08838834764831845f;  // 128^-0.5 (pre-scale Q for attention)
  const float qr0 = (qn0 * cc.x - qn1 * ssn.x) * ATT;
  const float qr1 = (qn1 * cc.y + qn0 * ssn.y) * ATT;
  const float kr0 = kn0 * cc.x - kn1 * ssn.x;
  const float kr1 = kn1 * cc.y + kn0 * ssn.y;

  const size_t dst = ((size_t)bh * S_LEN + s) * 128 + 2 * l;
  *(u32*)(Qb + dst) = (u32)f2bf(qr0) | ((u32)f2bf(qr1) << 16);
  *(u32*)(Kb + dst) = (u32)f2bf(kr0) | ((u32)f2bf(kr1) << 16);
  *(u32*)(Vb + dst) = vu;  // plain copy (bf16 passthrough)
}

// ---------------- SwiGLU: silu(m1)*m2 -> Cat[:, 2048:10240] ----------------
__global__ __launch_bounds__(256) void swiglu(const u16* __restrict__ proj,
                                              u16* __restrict__ Cat) {
  const u32 i = blockIdx.x * 256 + threadIdx.x;  // quad index, total 4096*8192/4
  const u32 r = i >> 11;
  const u32 c = (i & 2047) * 4;
  const u16* p1 = proj + (size_t)r * NPROJ + 3 * QDIM + c;
  const uint2 a = *(const uint2*)p1;
  const uint2 bv = *(const uint2*)(p1 + 8192);
  const float a0 = bf2f(a.x & 0xffff), a1 = bf2f(a.x >> 16);
  const float a2 = bf2f(a.y & 0xffff), a3 = bf2f(a.y >> 16);
  const float b0 = bf2f(bv.x & 0xffff), b1 = bf2f(bv.x >> 16);
  const float b2 = bf2f(bv.y & 0xffff), b3 = bf2f(bv.y >> 16);
  const float o0 = a0 / (1.f + __expf(-a0)) * b0;
  const float o1 = a1 / (1.f + __expf(-a1)) * b1;
  const float o2 = a2 / (1.f + __expf(-a2)) * b2;
  const float o3 = a3 / (1.f + __expf(-a3)) * b3;
  uint2 o;
  o.x = (u32)f2bf(o0) | ((u32)f2bf(o1) << 16);
  o.y = (u32)f2bf(o2) | ((u32)f2bf(o3) << 16);
  *(uint2*)(Cat + (size_t)r * NCAT + QDIM + c) = o;
}

// ---------------- flash attention: 4 waves x 32 q-rows, KV tile = 64 ----------------
// Qb/Kb: [bh][s][128] bf16 (Q pre-scaled); Vt: [bh][128][s] bf16.
// Out -> Cat[:, 0:2048] at [b*S+s][h*128+d].
__global__ __launch_bounds__(256, 2) void attn_fwd(const u16* __restrict__ Qb,
                                                   const u16* __restrict__ Kb,
                                                   const u16* __restrict__ Vt,
                                                   u16* __restrict__ Cat) {
  __shared__ u16 Ks[64 * 128];   // [key][d], rows 256B (16 granules), swz g^=key&7
  __shared__ u16 Vs[128 * 64];   // [d][key], rows 128B (8 granules),  swz g^=d&7
  __shared__ u16 Ps[4][32 * 64]; // per-wave P [q][key], rows 128B,    swz g^=q&7

  const int t = threadIdx.x;
  const int l = t & 63;
  const int w = t >> 6;
  const int lr = l & 15;
  const int lg = l >> 4;
  const int qt = blockIdx.x;
  const int bh = blockIdx.y;
  const int b = bh >> 4;
  const int h = bh & 15;
  const int q0 = qt * 128 + w * 32;

  bf16x8 qf[2][4];
#pragma unroll
  for (int im = 0; im < 2; ++im)
#pragma unroll
    for (int kc = 0; kc < 4; ++kc)
      qf[im][kc] =
          *(const bf16x8*)&Qb[((size_t)bh * S_LEN + q0 + im * 16 + lr) * 128 + kc * 32 + lg * 8];

  f32x4 oacc[2][8] = {};
  float mrun[2][4], lrun[2][4];
#pragma unroll
  for (int im = 0; im < 2; ++im)
#pragma unroll
    for (int r = 0; r < 4; ++r) {
      mrun[im][r] = -1e30f;
      lrun[im][r] = 0.f;
    }

  const int obase = w * 1024 + l * 16;
  u16* P = Ps[w];

  for (int kt = 0; kt < 32; ++kt) {
    const int kk0 = kt * 64;
#pragma unroll
    for (int rnd = 0; rnd < 4; ++rnd) {
      const int o = obase + rnd * 4096;
      {
        const int key = o >> 8;
        const int g = (o & 255) >> 4;
        const int gs = g ^ (key & 7);
        gld16(Kb + ((size_t)bh * S_LEN + kk0 + key) * 128 + gs * 8, &Ks[rnd * 2048 + w * 512]);
      }
      {
        const int d = o >> 7;
        const int g = (o & 127) >> 4;
        const int gs = g ^ (d & 7);
        gld16(Vt + ((size_t)bh * 128 + d) * S_LEN + kk0 + gs * 8, &Vs[rnd * 2048 + w * 512]);
      }
    }
    __syncthreads();

    // QK^T
    f32x4 sf[2][4] = {};
#pragma unroll
    for (int j = 0; j < 4; ++j) {
      const int kr = j * 16 + lr;
      bf16x8 kf[4];
#pragma unroll
      for (int kc = 0; kc < 4; ++kc)
        kf[kc] = *(const bf16x8*)&Ks[kr * 128 + (((kc * 4 + lg) ^ (kr & 7)) * 8)];
#pragma unroll
      for (int kc = 0; kc < 4; ++kc)
#pragma unroll
        for (int im = 0; im < 2; ++im)
          sf[im][j] = MFMA16(qf[im][kc], kf[kc], sf[im][j]);
    }

    // online softmax (row lives in 16 lanes sharing lg; reduce over low-4 lane bits)
#pragma unroll
    for (int im = 0; im < 2; ++im) {
#pragma unroll
      for (int r = 0; r < 4; ++r) {
        float v = fmaxf(fmaxf(sf[im][0][r], sf[im][1][r]), fmaxf(sf[im][2][r], sf[im][3][r]));
        v = fmaxf(v, __shfl_xor(v, 1));
        v = fmaxf(v, __shfl_xor(v, 2));
        v = fmaxf(v, __shfl_xor(v, 4));
        v = fmaxf(v, __shfl_xor(v, 8));
        const float mnew = fmaxf(mrun[im][r], v);
        const float alpha = __expf(mrun[im][r] - mnew);
        mrun[im][r] = mnew;
        float psum = 0.f;
#pragma unroll
        for (int j = 0; j < 4; ++j) {
          const float pv = __expf(sf[im][j][r] - mnew);
          sf[im][j][r] = pv;
          psum += pv;
        }
        psum += __shfl_xor(psum, 1);
        psum += __shfl_xor(psum, 2);
        psum += __shfl_xor(psum, 4);
        psum += __shfl_xor(psum, 8);
        lrun[im][r] = lrun[im][r] * alpha + psum;
#pragma unroll
        for (int df = 0; df < 8; ++df) oacc[im][df][r] *= alpha;
      }
    }

    // P -> per-wave LDS (swizzled for the A-frag read)
#pragma unroll
    for (int im = 0; im < 2; ++im)
#pragma unroll
      for (int j = 0; j < 4; ++j)
#pragma unroll
        for (int r = 0; r < 4; ++r) {
          const int q = im * 16 + lg * 4 + r;
          const int key = j * 16 + lr;
          const int g = key >> 3;
          P[q * 64 + ((g ^ (q & 7)) * 8) + (key & 7)] = f2bf(sf[im][j][r]);
        }

    // PV
#pragma unroll
    for (int kc = 0; kc < 2; ++kc) {
      bf16x8 pa[2];
#pragma unroll
      for (int im = 0; im < 2; ++im) {
        const int q = im * 16 + lr;
        pa[im] = *(const bf16x8*)&P[q * 64 + (((kc * 4 + lg) ^ (q & 7)) * 8)];
      }
#pragma unroll
      for (int df = 0; df < 8; ++df) {
        const int d = df * 16 + lr;
        const bf16x8 vb = *(const bf16x8*)&Vs[d * 64 + (((kc * 4 + lg) ^ (d & 7)) * 8)];
#pragma unroll
        for (int im = 0; im < 2; ++im) oacc[im][df] = MFMA16(pa[im], vb, oacc[im][df]);
      }
    }
    __syncthreads();
  }

  // epilogue: normalize and write into Cat[:, 0:2048]
#pragma unroll
  for (int im = 0; im < 2; ++im)
#pragma unroll
    for (int r = 0; r < 4; ++r) {
      const float inv = 1.0f / lrun[im][r];
      const int row = b * S_LEN + q0 + im * 16 + lg * 4 + r;
#pragma unroll
      for (int df = 0; df < 8; ++df) {
        const int col = h * 128 + df * 16 + lr;
        Cat[(size_t)row * NCAT + col] = f2bf(oacc[im][df][r] * inv);
      }
    }
}

// ---------------- launch ----------------
extern "C" void kernel_launch(void* const* d_in, const int* in_sizes, int n_in, void* d_out,
                              int out_size, void* d_ws, size_t ws_size, hipStream_t stream) {
  (void)in_sizes; (void)n_in; (void)out_size; (void)ws_size;
  const float* hs = (const float*)d_in[0];
  const float* rcos = (const float*)d_in[1];
  const float* rsin = (const float*)d_in[2];
  const float* Wqkv = (const float*)d_in[3];
  const float* wq = (const float*)d_in[4];
  const float* wk = (const float*)d_in[5];
  const float* Wout = (const float*)d_in[6];
  const float* bout = (const float*)d_in[7];
  float* out = (float*)d_out;

  char* ws = (char*)d_ws;
  size_t off = 0;
  auto nxt = [&](size_t bytes) {
    char* p = ws + off;
    off += (bytes + 255) & ~(size_t)255;
    return p;
  };
  u16* Xb = (u16*)nxt((size_t)MROWS * QDIM * 2);         // 16.8 MB
  u16* Wqkvt = (u16*)nxt((size_t)NPROJ * QDIM * 2);      // 92.3 MB
  u16* Woutt = (u16*)nxt((size_t)QDIM * NCAT * 2);       // 41.9 MB
  u16* proj = (u16*)nxt((size_t)MROWS * NPROJ * 2);      // 184.5 MB
  u16* Qb = (u16*)nxt((size_t)NBH * S_LEN * D_HEAD * 2); // 16.8 MB
  u16* Kb = (u16*)nxt((size_t)NBH * S_LEN * D_HEAD * 2);
  u16* Vb = (u16*)nxt((size_t)NBH * S_LEN * D_HEAD * 2);
  u16* Vt = (u16*)nxt((size_t)NBH * S_LEN * D_HEAD * 2);
  u16* Cat = (u16*)nxt((size_t)MROWS * NCAT * 2);        // 83.9 MB  (total ~465 MB)

  // 1) convert / transpose weights+activations to bf16
  f32_to_bf16<<<(MROWS * QDIM / 4) / 256, 256, 0, stream>>>(hs, Xb);
  transpose_f32_bf16<<<dim3(NPROJ / 64, QDIM / 64), 256, 0, stream>>>(Wqkv, Wqkvt, QDIM, NPROJ);
  transpose_f32_bf16<<<dim3(QDIM / 64, NCAT / 64), 256, 0, stream>>>(Wout, Woutt, NCAT, QDIM);

  // 2) fused QKV+MLP projection
  gemm_bt<0><<<dim3(NPROJ / 128, MROWS / 128), 256, 0, stream>>>(Xb, Wqkvt, proj, nullptr,
                                                                 NPROJ, QDIM);
  // 3) RMSNorm + RoPE + QKV split; V transpose for PV reads
  norm_rope<<<MROWS * NHEADS / 4, 256, 0, stream>>>(proj, rcos, rsin, wq, wk, Qb, Kb, Vb);
  transpose_bf16_b<<<dim3(D_HEAD / 64, S_LEN / 64, NBH), 256, 0, stream>>>(Vb, Vt, S_LEN, D_HEAD);

  // 4) SwiGLU into concat buffer
  swiglu<<<(MROWS * 8192 / 4) / 256, 256, 0, stream>>>(proj, Cat);

  // 5) flash attention into concat buffer
  attn_fwd<<<dim3(S_LEN / 128, NBH), 256, 0, stream>>>(Qb, Kb, Vt, Cat);

  // 6) output projection + bias (f32 out)
  gemm_bt<1><<<dim3(QDIM / 128, MROWS / 128), 256, 0, stream>>>(Cat, Woutt, out, bout,
                                                                QDIM, NCAT);
}